// Round 3
// baseline (71.517 us; speedup 1.0000x reference)
//
#include <hip/hip_runtime.h>

// Problem constants (from reference): B=8, N=4096, D=3
#define B_ 8
#define N_ 4096
#define P_ 2                          // own points per lane
#define OWN_PER_BLOCK (64 * P_)       // 128
#define OWN_CHUNKS (N_ / OWN_PER_BLOCK) // 32
#define OPP_CHUNKS 4                  // opposite range split across blocks
#define OPP_PER_BLOCK (N_ / OPP_CHUNKS)   // 1024
#define OPP_PER_WAVE (OPP_PER_BLOCK / 4)  // 256

__global__ void chamfer_init_acc(double* acc) {
    if (threadIdx.x < 2) acc[threadIdx.x] = 0.0;
}

// Partial-min kernel. Grid: (OWN_CHUNKS, B_*OPP_CHUNKS, 2) = 32*32*2 = 2048
// blocks -> 8 blocks/CU -> 8 waves/SIMD (full wave occupancy @ 36 VGPR).
// dir 0: own = y (j), opp = x -> later acc[0]   (min over axis 1)
// dir 1: own = x (i), opp = y -> later acc[1]   (min over axis 2)
// Block: 4 waves; wave s scans opp sub-range of 256 points; lane l owns 2
// own-points. Partial mins written (no atomics) to part[dir][b][oc][N].
__global__ __launch_bounds__(256) void chamfer_min_kernel(
        const float* __restrict__ x, const float* __restrict__ y,
        float* __restrict__ part) {
    const int dir = blockIdx.z;
    const int b   = blockIdx.y >> 2;
    const int oc  = blockIdx.y & 3;
    const int base = blockIdx.x * OWN_PER_BLOCK;

    const float* own = dir ? x : y;
    const float* opp = dir ? y : x;

    const int t = threadIdx.x;
    const int l = t & 63;
    const int s = t >> 6;

    // Per-lane own points (12 B/lane, coalesced).
    float px[P_], py[P_], pz[P_];
#pragma unroll
    for (int p = 0; p < P_; ++p) {
        const float* op = own + ((size_t)b * N_ + base + p * 64 + l) * 3;
        px[p] = op[0]; py[p] = op[1]; pz[p] = op[2];
    }

    float m[P_][4];
#pragma unroll
    for (int p = 0; p < P_; ++p)
#pragma unroll
        for (int c = 0; c < 4; ++c) m[p][c] = 1e30f;

    const float* ob = opp + (size_t)b * N_ * 3;
    const int kbeg = oc * OPP_PER_BLOCK + s * OPP_PER_WAVE;
    const int kend = kbeg + OPP_PER_WAVE;

#pragma unroll 4
    for (int k = kbeg; k < kend; k += 4) {
        // 4 opposite points = 12 consecutive floats, wave-uniform address.
        const float4* q = reinterpret_cast<const float4*>(ob + (size_t)k * 3);
        const float4 A = q[0], Bv = q[1], C = q[2];
#pragma unroll
        for (int p = 0; p < P_; ++p) {
            { float dx = A.x  - px[p], dy = A.y  - py[p], dz = A.z  - pz[p];
              float d = dx*dx + dy*dy + dz*dz; m[p][0] = fminf(m[p][0], d); }
            { float dx = A.w  - px[p], dy = Bv.x - py[p], dz = Bv.y - pz[p];
              float d = dx*dx + dy*dy + dz*dz; m[p][1] = fminf(m[p][1], d); }
            { float dx = Bv.z - px[p], dy = Bv.w - py[p], dz = C.x  - pz[p];
              float d = dx*dx + dy*dy + dz*dz; m[p][2] = fminf(m[p][2], d); }
            { float dx = C.y  - px[p], dy = C.z  - py[p], dz = C.w  - pz[p];
              float d = dx*dx + dy*dy + dz*dz; m[p][3] = fminf(m[p][3], d); }
        }
    }

    // Cross-wave min reduction, then one coalesced partial write.
    __shared__ float red[4][OWN_PER_BLOCK];
#pragma unroll
    for (int p = 0; p < P_; ++p)
        red[s][p * 64 + l] = fminf(fminf(m[p][0], m[p][1]), fminf(m[p][2], m[p][3]));
    __syncthreads();

    if (t < OWN_PER_BLOCK) {
        float mn = fminf(fminf(red[0][t], red[1][t]), fminf(red[2][t], red[3][t]));
        part[(((size_t)dir * B_ + b) * OPP_CHUNKS + oc) * N_ + base + t] = mn;
    }
}

// Combine the OPP_CHUNKS partials, apply mask, accumulate in f64.
// 2*B_*N_ = 65536 items -> 256 blocks x 256 threads.
__global__ __launch_bounds__(256) void chamfer_reduce_kernel(
        const float* __restrict__ part,
        const float* __restrict__ xm, const float* __restrict__ ym,
        double* __restrict__ acc) {
    const int id  = blockIdx.x * 256 + threadIdx.x;
    const int dir = id >> 15;           // uniform across a wave (32768 % 64 == 0)
    const int rem = id & 32767;
    const int b   = rem >> 12;
    const int n   = rem & (N_ - 1);

    const float* msk = dir ? ym : xm;

    float mn = 1e30f;
#pragma unroll
    for (int oc = 0; oc < OPP_CHUNKS; ++oc)
        mn = fminf(mn, part[(((size_t)dir * B_ + b) * OPP_CHUNKS + oc) * N_ + n]);

    double val = (double)(msk[(size_t)b * N_ + n] * mn);
    for (int off = 32; off; off >>= 1)
        val += __shfl_down(val, off);
    if ((threadIdx.x & 63) == 0)
        atomicAdd(&acc[dir], val);
}

__global__ void chamfer_finalize(const double* __restrict__ acc, float* __restrict__ out) {
    double d = (acc[0] - acc[1]) / (double)(B_ * N_);
    out[0] = (float)(d * d);
}

extern "C" void kernel_launch(void* const* d_in, const int* in_sizes, int n_in,
                              void* d_out, int out_size, void* d_ws, size_t ws_size,
                              hipStream_t stream) {
    const float* x  = (const float*)d_in[0];
    const float* y  = (const float*)d_in[1];
    const float* xm = (const float*)d_in[2];
    const float* ym = (const float*)d_in[3];
    float* out = (float*)d_out;

    double* acc = (double*)d_ws;                       // 16 B
    float* part = (float*)((char*)d_ws + 256);         // 2*8*4*4096*4 B = 1 MB

    chamfer_init_acc<<<1, 64, 0, stream>>>(acc);

    dim3 grid(OWN_CHUNKS, B_ * OPP_CHUNKS, 2);         // 32 x 32 x 2 = 2048 blocks
    chamfer_min_kernel<<<grid, 256, 0, stream>>>(x, y, part);

    chamfer_reduce_kernel<<<(2 * B_ * N_) / 256, 256, 0, stream>>>(part, xm, ym, acc);

    chamfer_finalize<<<1, 1, 0, stream>>>(acc, out);
}

// Round 5
// 64.876 us; speedup vs baseline: 1.1024x; 1.1024x over previous
//
#include <hip/hip_runtime.h>

// Problem constants (from reference): B=8, N=4096, D=3
#define B_ 8
#define N_ 4096
#define OWN_PER_BLOCK 128               // 2 own points per lane
#define OWN_CHUNKS (N_ / OWN_PER_BLOCK) // 32
#define OPP_CHUNKS 4                    // opposite range split across blocks
#define OPP_PER_BLOCK (N_ / OPP_CHUNKS) // 1024
#define OPP_PER_WAVE (OPP_PER_BLOCK / 4) // 256

typedef __attribute__((ext_vector_type(16))) float fv16;

// Prep: tab[src][b][n] = (qx, qy, qz, |q|^2) padded 16B records; src 0=x, 1=y.
// (w = |q|^2 is unused this round; staged for a dot-form variant.)
// Also zero-inits the f64 accumulators (block 0).
__global__ __launch_bounds__(256) void chamfer_prep(
        const float* __restrict__ x, const float* __restrict__ y,
        float4* __restrict__ tab, double* __restrict__ acc) {
    const int id  = blockIdx.x * 256 + threadIdx.x;  // 0..65535
    const int src = id >> 15;
    const int rem = id & 32767;                      // b*N + n
    const float* s_ = src ? y : x;
    const float a = s_[3 * rem], b = s_[3 * rem + 1], c = s_[3 * rem + 2];
    tab[id] = make_float4(a, b, c, a * a + b * b + c * c);
    if (blockIdx.x == 0 && threadIdx.x < 2) acc[threadIdx.x] = 0.0;
}

// Issue 2 scalar 64B loads (8 padded points). "=&s" early-clobber: outputs
// cannot overlap the address pair (round-4 corruption bug #1).
#define ISSUE2(B0, B1, AD) \
    asm volatile("s_load_dwordx16 %0, %2, 0x0\n\t" \
                 "s_load_dwordx16 %1, %2, 0x40" \
                 : "=&s"(B0), "=&s"(B1) : "s"(AD))

// Wait for all outstanding scalar loads (completes A0/A1), then issue the
// next chunk into B0/B1. A0/A1 tied "+s" so their consumers stay below the
// wait; early-clobber keeps B0/B1 off AD and A0/A1.
#define WAIT_ISSUE2(B0, B1, A0, A1, AD) \
    asm volatile("s_waitcnt lgkmcnt(0)\n\t" \
                 "s_load_dwordx16 %0, %4, 0x0\n\t" \
                 "s_load_dwordx16 %1, %4, 0x40" \
                 : "=&s"(B0), "=&s"(B1), "+s"(A0), "+s"(A1) : "s"(AD))

// Drain only — no new issues (fixes round-4 dangling-load bug #2).
#define WAIT_ONLY(A0, A1) \
    asm volatile("s_waitcnt lgkmcnt(0)" : "+s"(A0), "+s"(A1))

// Direct-form eval of point J (components 4J..4J+2) against both own points.
// 14 VALU per point: 6 sub + 2 mul + 4 fma + 2 min; q* stay in SGPRs and are
// consumed as the one-allowed scalar operand of v_sub_f32.
#define EVAL_PT(AV, J) do { \
    const float qx = (AV)[4 * (J) + 0]; \
    const float qy = (AV)[4 * (J) + 1]; \
    const float qz = (AV)[4 * (J) + 2]; \
    float dx0 = qx - px0, dy0 = qy - py0, dz0 = qz - pz0; \
    float d0  = dx0 * dx0 + dy0 * dy0 + dz0 * dz0; \
    float dx1 = qx - px1, dy1 = qy - py1, dz1 = qz - pz1; \
    float d1  = dx1 * dx1 + dy1 * dy1 + dz1 * dz1; \
    if ((J) & 1) { m0o = fminf(m0o, d0); m1o = fminf(m1o, d1); } \
    else         { m0e = fminf(m0e, d0); m1e = fminf(m1e, d1); } \
} while (0)

#define COMP8(A0, A1) do { \
    EVAL_PT(A0, 0); EVAL_PT(A0, 1); EVAL_PT(A0, 2); EVAL_PT(A0, 3); \
    EVAL_PT(A1, 0); EVAL_PT(A1, 1); EVAL_PT(A1, 2); EVAL_PT(A1, 3); \
} while (0)

// dir 0: own = y (j), opp = x (tab slice 0) -> acc[0]  (min over axis 1)
// dir 1: own = x (i), opp = y (tab slice 1) -> acc[1]  (min over axis 2)
// Grid (OWN_CHUNKS, B_*OPP_CHUNKS, 2) = 2048 blocks = 8 waves/SIMD.
// Opp data consumed from SGPRs (s_load_dwordx16, exact 2-deep pipeline).
__global__ __launch_bounds__(256) void chamfer_min_kernel(
        const float* __restrict__ x, const float* __restrict__ y,
        const float4* __restrict__ tab, float* __restrict__ part) {
    const int dir  = blockIdx.z;
    const int b    = blockIdx.y >> 2;
    const int oc   = blockIdx.y & 3;
    const int base = blockIdx.x * OWN_PER_BLOCK;

    const float* own = dir ? x : y;

    const int t = threadIdx.x;
    const int l = t & 63;
    const int su = __builtin_amdgcn_readfirstlane(t >> 6);  // wave id, SGPR

    // Per-lane own points (coalesced 12 B/lane).
    const float* op0 = own + ((size_t)b * N_ + base + l) * 3;
    const float* op1 = op0 + 64 * 3;
    const float px0 = op0[0], py0 = op0[1], pz0 = op0[2];
    const float px1 = op1[0], py1 = op1[1], pz1 = op1[2];

    float m0e = 1e30f, m0o = 1e30f, m1e = 1e30f, m1o = 1e30f;

    // Uniform SGPR address of this wave's 256-point table slice.
    const float4* tslice = tab + (((size_t)dir * B_ + b) * N_
                                  + oc * OPP_PER_BLOCK + su * OPP_PER_WAVE);
    unsigned long long ad = (unsigned long long)tslice;

    // 32 chunks of 8 points. Pipeline: 1 + 15*2 + 1 issues = 32 exactly;
    // every issue is waited; no overread past the slice.
    fv16 a0, a1, b0, b1;
    ISSUE2(a0, a1, ad); ad += 128;
#pragma unroll 1
    for (int it = 0; it < 15; ++it) {
        WAIT_ISSUE2(b0, b1, a0, a1, ad); ad += 128;
        COMP8(a0, a1);
        WAIT_ISSUE2(a0, a1, b0, b1, ad); ad += 128;
        COMP8(b0, b1);
    }
    WAIT_ISSUE2(b0, b1, a0, a1, ad);    // wait chunk 30, issue chunk 31
    COMP8(a0, a1);                      // chunk 30
    WAIT_ONLY(b0, b1);                  // drain chunk 31
    COMP8(b0, b1);                      // chunk 31

    // Cross-wave min reduction; one coalesced partial write.
    __shared__ float red[4][OWN_PER_BLOCK];
    red[su][l]      = fminf(m0e, m0o);
    red[su][64 + l] = fminf(m1e, m1o);
    __syncthreads();

    if (t < OWN_PER_BLOCK) {
        float mn = fminf(fminf(red[0][t], red[1][t]), fminf(red[2][t], red[3][t]));
        part[(((size_t)dir * B_ + b) * OPP_CHUNKS + oc) * N_ + base + t] = mn;
    }
}

// Combine OPP_CHUNKS partials, apply mask, accumulate in f64.
__global__ __launch_bounds__(256) void chamfer_reduce_kernel(
        const float* __restrict__ part,
        const float* __restrict__ xm, const float* __restrict__ ym,
        double* __restrict__ acc) {
    const int id  = blockIdx.x * 256 + threadIdx.x;
    const int dir = id >> 15;            // uniform per wave
    const int rem = id & 32767;
    const int b   = rem >> 12;
    const int n   = rem & (N_ - 1);

    const float* msk = dir ? ym : xm;

    float mn = 1e30f;
#pragma unroll
    for (int oc = 0; oc < OPP_CHUNKS; ++oc)
        mn = fminf(mn, part[(((size_t)dir * B_ + b) * OPP_CHUNKS + oc) * N_ + n]);

    double val = (double)(msk[(size_t)b * N_ + n] * mn);
    for (int off = 32; off; off >>= 1)
        val += __shfl_down(val, off);
    if ((threadIdx.x & 63) == 0)
        atomicAdd(&acc[dir], val);
}

__global__ void chamfer_finalize(const double* __restrict__ acc, float* __restrict__ out) {
    double d = (acc[0] - acc[1]) / (double)(B_ * N_);
    out[0] = (float)(d * d);
}

extern "C" void kernel_launch(void* const* d_in, const int* in_sizes, int n_in,
                              void* d_out, int out_size, void* d_ws, size_t ws_size,
                              hipStream_t stream) {
    const float* x  = (const float*)d_in[0];
    const float* y  = (const float*)d_in[1];
    const float* xm = (const float*)d_in[2];
    const float* ym = (const float*)d_in[3];
    float* out = (float*)d_out;

    double* acc = (double*)d_ws;                            // 16 B
    float4* tab = (float4*)((char*)d_ws + 256);             // 2*8*4096*16 = 1 MB
    float*  prt = (float*)((char*)d_ws + 256 + (size_t)2 * B_ * N_ * 16); // 1 MB

    chamfer_prep<<<(2 * B_ * N_) / 256, 256, 0, stream>>>(x, y, tab, acc);

    dim3 grid(OWN_CHUNKS, B_ * OPP_CHUNKS, 2);              // 2048 blocks
    chamfer_min_kernel<<<grid, 256, 0, stream>>>(x, y, tab, prt);

    chamfer_reduce_kernel<<<(2 * B_ * N_) / 256, 256, 0, stream>>>(prt, xm, ym, acc);

    chamfer_finalize<<<1, 1, 0, stream>>>(acc, out);
}

// Round 6
// 59.418 us; speedup vs baseline: 1.2036x; 1.0918x over previous
//
#include <hip/hip_runtime.h>

// Problem constants (from reference): B=8, N=4096, D=3
#define B_ 8
#define N_ 4096
#define OWN_PER_BLOCK 128               // 2 own points per lane
#define OWN_CHUNKS (N_ / OWN_PER_BLOCK) // 32
#define OPP_CHUNKS 4                    // opposite range split across blocks
#define OPP_PER_BLOCK (N_ / OPP_CHUNKS) // 1024
#define OPP_PER_WAVE (OPP_PER_BLOCK / 4) // 256
#define RED_BLOCKS ((2 * B_ * N_) / 256) // 256

typedef __attribute__((ext_vector_type(16))) float fv16;

// Prep: tab[src][b][n] = (-2qx, -2qy, -2qz, |q|^2); src 0 = x, 1 = y.
// Also zero-inits the f64 accumulators and the reduce completion counter.
__global__ __launch_bounds__(256) void chamfer_prep(
        const float* __restrict__ x, const float* __restrict__ y,
        float4* __restrict__ tab, double* __restrict__ acc,
        unsigned* __restrict__ cnt) {
    const int id  = blockIdx.x * 256 + threadIdx.x;  // 0..65535
    const int src = id >> 15;
    const int rem = id & 32767;                      // b*N + n
    const float* s_ = src ? y : x;
    const float a = s_[3 * rem], b = s_[3 * rem + 1], c = s_[3 * rem + 2];
    tab[id] = make_float4(-2.f * a, -2.f * b, -2.f * c, a * a + b * b + c * c);
    if (blockIdx.x == 0) {
        if (threadIdx.x < 2) acc[threadIdx.x] = 0.0;
        if (threadIdx.x == 2) *cnt = 0u;
    }
}

// Issue 2 scalar 64B loads (8 points). "=&s" early-clobber: outputs cannot
// overlap the address pair.
#define ISSUE2(B0, B1, AD) \
    asm volatile("s_load_dwordx16 %0, %2, 0x0\n\t" \
                 "s_load_dwordx16 %1, %2, 0x40" \
                 : "=&s"(B0), "=&s"(B1) : "s"(AD))

// Wait for all outstanding scalar loads (completes A0/A1), then issue the
// next chunk into B0/B1. A0/A1 tied "+s" so consumers stay below the wait.
#define WAIT_ISSUE2(B0, B1, A0, A1, AD) \
    asm volatile("s_waitcnt lgkmcnt(0)\n\t" \
                 "s_load_dwordx16 %0, %4, 0x0\n\t" \
                 "s_load_dwordx16 %1, %4, 0x40" \
                 : "=&s"(B0), "=&s"(B1), "+s"(A0), "+s"(A1) : "s"(AD))

// Drain only — no new issues.
#define WAIT_ONLY(A0, A1) \
    asm volatile("s_waitcnt lgkmcnt(0)" : "+s"(A0), "+s"(A1))

// Dot-form eval of point J: e = |q|^2 - 2 q.p  (true d^2 = e + |p|^2, added
// once in the epilogue). 3 FMA + 1 min per own point + 1 shared v_mov.
#define EVAL_PT(AV, J) do { \
    const float nx = (AV)[4 * (J) + 0]; \
    const float ny = (AV)[4 * (J) + 1]; \
    const float nz = (AV)[4 * (J) + 2]; \
    const float w  = (AV)[4 * (J) + 3]; \
    float e0 = fmaf(nz, pz0, w); \
    e0 = fmaf(ny, py0, e0); \
    e0 = fmaf(nx, px0, e0); \
    float e1 = fmaf(nz, pz1, w); \
    e1 = fmaf(ny, py1, e1); \
    e1 = fmaf(nx, px1, e1); \
    if ((J) & 1) { m0o = fminf(m0o, e0); m1o = fminf(m1o, e1); } \
    else         { m0e = fminf(m0e, e0); m1e = fminf(m1e, e1); } \
} while (0)

#define COMP8(A0, A1) do { \
    EVAL_PT(A0, 0); EVAL_PT(A0, 1); EVAL_PT(A0, 2); EVAL_PT(A0, 3); \
    EVAL_PT(A1, 0); EVAL_PT(A1, 1); EVAL_PT(A1, 2); EVAL_PT(A1, 3); \
} while (0)

// dir 0: own = y (j), opp = x (tab slice 0) -> acc[0]  (min over axis 1)
// dir 1: own = x (i), opp = y (tab slice 1) -> acc[1]  (min over axis 2)
// Grid (OWN_CHUNKS, B_*OPP_CHUNKS, 2) = 2048 blocks = 8 blocks/CU.
// Opp data consumed from SGPRs (s_load_dwordx16, exact 2-deep pipeline).
__global__ __launch_bounds__(256) void chamfer_min_kernel(
        const float* __restrict__ x, const float* __restrict__ y,
        const float4* __restrict__ tab, float* __restrict__ part) {
    const int dir  = blockIdx.z;
    const int b    = blockIdx.y >> 2;
    const int oc   = blockIdx.y & 3;
    const int base = blockIdx.x * OWN_PER_BLOCK;

    const float* own = dir ? x : y;

    const int t = threadIdx.x;
    const int l = t & 63;
    const int su = __builtin_amdgcn_readfirstlane(t >> 6);  // wave id, SGPR

    // Per-lane own points (coalesced 12 B/lane).
    const float* op0 = own + ((size_t)b * N_ + base + l) * 3;
    const float* op1 = op0 + 64 * 3;
    const float px0 = op0[0], py0 = op0[1], pz0 = op0[2];
    const float px1 = op1[0], py1 = op1[1], pz1 = op1[2];

    float m0e = 1e30f, m0o = 1e30f, m1e = 1e30f, m1o = 1e30f;

    // Uniform SGPR address of this wave's 256-point table slice.
    const float4* tslice = tab + (((size_t)dir * B_ + b) * N_
                                  + oc * OPP_PER_BLOCK + su * OPP_PER_WAVE);
    unsigned long long ad = (unsigned long long)tslice;

    // 32 chunks of 8 points. Pipeline: 1 + 15*2 + 1 issues = 32 exactly;
    // every issue is waited; no overread past the slice.
    fv16 a0, a1, b0, b1;
    ISSUE2(a0, a1, ad); ad += 128;
#pragma unroll 1
    for (int it = 0; it < 15; ++it) {
        WAIT_ISSUE2(b0, b1, a0, a1, ad); ad += 128;
        COMP8(a0, a1);
        WAIT_ISSUE2(a0, a1, b0, b1, ad); ad += 128;
        COMP8(b0, b1);
    }
    WAIT_ISSUE2(b0, b1, a0, a1, ad);    // wait chunk 30, issue chunk 31
    COMP8(a0, a1);                      // chunk 30
    WAIT_ONLY(b0, b1);                  // drain chunk 31
    COMP8(b0, b1);                      // chunk 31

    // d^2 = min_e + |p|^2; cross-wave min; one coalesced partial write.
    __shared__ float red[4][OWN_PER_BLOCK];
    red[su][l]      = fminf(m0e, m0o) + (px0 * px0 + py0 * py0 + pz0 * pz0);
    red[su][64 + l] = fminf(m1e, m1o) + (px1 * px1 + py1 * py1 + pz1 * pz1);
    __syncthreads();

    if (t < OWN_PER_BLOCK) {
        float mn = fminf(fminf(red[0][t], red[1][t]), fminf(red[2][t], red[3][t]));
        part[(((size_t)dir * B_ + b) * OPP_CHUNKS + oc) * N_ + base + t] = mn;
    }
}

// Combine OPP_CHUNKS partials, apply mask, accumulate in f64; the last block
// to finish also writes the final scalar (fused finalize).
__global__ __launch_bounds__(256) void chamfer_reduce_kernel(
        const float* __restrict__ part,
        const float* __restrict__ xm, const float* __restrict__ ym,
        double* __restrict__ acc, unsigned* __restrict__ cnt,
        float* __restrict__ out) {
    const int id  = blockIdx.x * 256 + threadIdx.x;
    const int dir = id >> 15;            // uniform per wave
    const int rem = id & 32767;
    const int b   = rem >> 12;
    const int n   = rem & (N_ - 1);

    const float* msk = dir ? ym : xm;

    float mn = 1e30f;
#pragma unroll
    for (int oc = 0; oc < OPP_CHUNKS; ++oc)
        mn = fminf(mn, part[(((size_t)dir * B_ + b) * OPP_CHUNKS + oc) * N_ + n]);

    double val = (double)(msk[(size_t)b * N_ + n] * mn);
    for (int off = 32; off; off >>= 1)
        val += __shfl_down(val, off);
    if ((threadIdx.x & 63) == 0)
        atomicAdd(&acc[dir], val);

    __syncthreads();
    if (threadIdx.x == 0) {
        __threadfence();
        unsigned old = atomicAdd(cnt, 1u);
        if (old == RED_BLOCKS - 1) {
            __threadfence();
            double d = (acc[0] - acc[1]) / (double)(B_ * N_);
            out[0] = (float)(d * d);
        }
    }
}

extern "C" void kernel_launch(void* const* d_in, const int* in_sizes, int n_in,
                              void* d_out, int out_size, void* d_ws, size_t ws_size,
                              hipStream_t stream) {
    const float* x  = (const float*)d_in[0];
    const float* y  = (const float*)d_in[1];
    const float* xm = (const float*)d_in[2];
    const float* ym = (const float*)d_in[3];
    float* out = (float*)d_out;

    double*   acc = (double*)d_ws;                          // 16 B
    unsigned* cnt = (unsigned*)((char*)d_ws + 16);          // 4 B
    float4*   tab = (float4*)((char*)d_ws + 256);           // 2*8*4096*16 = 1 MB
    float*    prt = (float*)((char*)d_ws + 256 + (size_t)2 * B_ * N_ * 16); // 1 MB

    chamfer_prep<<<RED_BLOCKS, 256, 0, stream>>>(x, y, tab, acc, cnt);

    dim3 grid(OWN_CHUNKS, B_ * OPP_CHUNKS, 2);              // 2048 blocks
    chamfer_min_kernel<<<grid, 256, 0, stream>>>(x, y, tab, prt);

    chamfer_reduce_kernel<<<RED_BLOCKS, 256, 0, stream>>>(prt, xm, ym, acc, cnt, out);
}

// Round 7
// 53.556 us; speedup vs baseline: 1.3354x; 1.1095x over previous
//
#include <hip/hip_runtime.h>

// Problem constants (from reference): B=8, N=4096, D=3
#define B_ 8
#define N_ 4096
#define P_ 4                            // own points per lane
#define OWN_PER_BLOCK (64 * P_)         // 256
#define OWN_CHUNKS (N_ / OWN_PER_BLOCK) // 16
#define OPP_CHUNKS 8                    // opposite range split across blocks
#define OPP_PER_BLOCK (N_ / OPP_CHUNKS) // 512
#define OPP_PER_WAVE (OPP_PER_BLOCK / 4) // 128
#define RED_BLOCKS ((2 * B_ * N_) / 256) // 256

typedef __attribute__((ext_vector_type(16))) float fv16;

// Prep: tab[src][b][n] = (-2qx, -2qy, -2qz, |q|^2); src 0 = x, 1 = y.
// Also zero-inits the f64 accumulators and the reduce completion counter.
__global__ __launch_bounds__(256) void chamfer_prep(
        const float* __restrict__ x, const float* __restrict__ y,
        float4* __restrict__ tab, double* __restrict__ acc,
        unsigned* __restrict__ cnt) {
    const int id  = blockIdx.x * 256 + threadIdx.x;  // 0..65535
    const int src = id >> 15;
    const int rem = id & 32767;                      // b*N + n
    const float* s_ = src ? y : x;
    const float a = s_[3 * rem], b = s_[3 * rem + 1], c = s_[3 * rem + 2];
    tab[id] = make_float4(-2.f * a, -2.f * b, -2.f * c, a * a + b * b + c * c);
    if (blockIdx.x == 0) {
        if (threadIdx.x < 2) acc[threadIdx.x] = 0.0;
        if (threadIdx.x == 2) *cnt = 0u;
    }
}

// Issue 2 scalar 64B loads (8 points). "=&s" early-clobber: outputs cannot
// overlap the address pair.
#define ISSUE2(B0, B1, AD) \
    asm volatile("s_load_dwordx16 %0, %2, 0x0\n\t" \
                 "s_load_dwordx16 %1, %2, 0x40" \
                 : "=&s"(B0), "=&s"(B1) : "s"(AD))

// Wait for all outstanding scalar loads (completes A0/A1), then issue the
// next chunk into B0/B1. A0/A1 tied "+s" so consumers stay below the wait.
// (Counted lgkmcnt is unsafe for SMEM — s_load returns may be out of order —
// so the pipeline is exactly 2-deep with lgkmcnt(0) waits.)
#define WAIT_ISSUE2(B0, B1, A0, A1, AD) \
    asm volatile("s_waitcnt lgkmcnt(0)\n\t" \
                 "s_load_dwordx16 %0, %4, 0x0\n\t" \
                 "s_load_dwordx16 %1, %4, 0x40" \
                 : "=&s"(B0), "=&s"(B1), "+s"(A0), "+s"(A1) : "s"(AD))

// Drain only — no new issues.
#define WAIT_ONLY(A0, A1) \
    asm volatile("s_waitcnt lgkmcnt(0)" : "+s"(A0), "+s"(A1))

// Dot-form eval of point J: e = |q|^2 - 2 q.p  (true d^2 = e + |p|^2, added
// once in the epilogue). Per point: 12 FMA + 4 min + 1 shared s->v mov.
#define EVAL_PT(AV, J) do { \
    const float nx = (AV)[4 * (J) + 0]; \
    const float ny = (AV)[4 * (J) + 1]; \
    const float nz = (AV)[4 * (J) + 2]; \
    const float w  = (AV)[4 * (J) + 3]; \
    float e0 = fmaf(nz, pz0, w); e0 = fmaf(ny, py0, e0); e0 = fmaf(nx, px0, e0); \
    float e1 = fmaf(nz, pz1, w); e1 = fmaf(ny, py1, e1); e1 = fmaf(nx, px1, e1); \
    float e2 = fmaf(nz, pz2, w); e2 = fmaf(ny, py2, e2); e2 = fmaf(nx, px2, e2); \
    float e3 = fmaf(nz, pz3, w); e3 = fmaf(ny, py3, e3); e3 = fmaf(nx, px3, e3); \
    if ((J) & 1) { m0o = fminf(m0o, e0); m1o = fminf(m1o, e1); \
                   m2o = fminf(m2o, e2); m3o = fminf(m3o, e3); } \
    else         { m0e = fminf(m0e, e0); m1e = fminf(m1e, e1); \
                   m2e = fminf(m2e, e2); m3e = fminf(m3e, e3); } \
} while (0)

#define COMP8(A0, A1) do { \
    EVAL_PT(A0, 0); EVAL_PT(A0, 1); EVAL_PT(A0, 2); EVAL_PT(A0, 3); \
    EVAL_PT(A1, 0); EVAL_PT(A1, 1); EVAL_PT(A1, 2); EVAL_PT(A1, 3); \
} while (0)

// dir 0: own = y (j), opp = x (tab slice 0) -> acc[0]  (min over axis 1)
// dir 1: own = x (i), opp = y (tab slice 1) -> acc[1]  (min over axis 2)
// Grid (OWN_CHUNKS, B_*OPP_CHUNKS, 2) = 16*64*2 = 2048 blocks = 8 blocks/CU.
// Each lane owns 4 points; wave scans a 128-point opp slice from SGPRs.
__global__ __launch_bounds__(256) void chamfer_min_kernel(
        const float* __restrict__ x, const float* __restrict__ y,
        const float4* __restrict__ tab, float* __restrict__ part) {
    const int dir  = blockIdx.z;
    const int b    = blockIdx.y >> 3;
    const int oc   = blockIdx.y & 7;
    const int base = blockIdx.x * OWN_PER_BLOCK;

    const float* own = dir ? x : y;

    const int t = threadIdx.x;
    const int l = t & 63;
    const int su = __builtin_amdgcn_readfirstlane(t >> 6);  // wave id, SGPR

    // Per-lane own points (coalesced 12 B/lane per group of 64).
    const float* op0 = own + ((size_t)b * N_ + base + l) * 3;
    const float px0 = op0[0],       py0 = op0[1],       pz0 = op0[2];
    const float px1 = op0[192],     py1 = op0[193],     pz1 = op0[194];
    const float px2 = op0[384],     py2 = op0[385],     pz2 = op0[386];
    const float px3 = op0[576],     py3 = op0[577],     pz3 = op0[578];

    float m0e = 1e30f, m0o = 1e30f, m1e = 1e30f, m1o = 1e30f;
    float m2e = 1e30f, m2o = 1e30f, m3e = 1e30f, m3o = 1e30f;

    // Uniform SGPR address of this wave's 128-point table slice.
    const float4* tslice = tab + (((size_t)dir * B_ + b) * N_
                                  + oc * OPP_PER_BLOCK + su * OPP_PER_WAVE);
    unsigned long long ad = (unsigned long long)tslice;

    // 16 chunks of 8 points. Pipeline: 1 + 7*2 + 1 issues = 16 exactly;
    // every issue is waited; no overread past the slice.
    fv16 a0, a1, b0, b1;
    ISSUE2(a0, a1, ad); ad += 128;
#pragma unroll 1
    for (int it = 0; it < 7; ++it) {
        WAIT_ISSUE2(b0, b1, a0, a1, ad); ad += 128;
        COMP8(a0, a1);
        WAIT_ISSUE2(a0, a1, b0, b1, ad); ad += 128;
        COMP8(b0, b1);
    }
    WAIT_ISSUE2(b0, b1, a0, a1, ad);    // wait chunk 14, issue chunk 15
    COMP8(a0, a1);                      // chunk 14
    WAIT_ONLY(b0, b1);                  // drain chunk 15
    COMP8(b0, b1);                      // chunk 15

    // d^2 = min_e + |p|^2; cross-wave min; one coalesced partial write.
    __shared__ float red[4][OWN_PER_BLOCK];
    red[su][l]       = fminf(m0e, m0o) + (px0 * px0 + py0 * py0 + pz0 * pz0);
    red[su][64 + l]  = fminf(m1e, m1o) + (px1 * px1 + py1 * py1 + pz1 * pz1);
    red[su][128 + l] = fminf(m2e, m2o) + (px2 * px2 + py2 * py2 + pz2 * pz2);
    red[su][192 + l] = fminf(m3e, m3o) + (px3 * px3 + py3 * py3 + pz3 * pz3);
    __syncthreads();

    {
        float mn = fminf(fminf(red[0][t], red[1][t]), fminf(red[2][t], red[3][t]));
        part[(((size_t)dir * B_ + b) * OPP_CHUNKS + oc) * N_ + base + t] = mn;
    }
}

// Combine OPP_CHUNKS partials, apply mask, accumulate in f64; the last block
// to finish also writes the final scalar (fused finalize).
__global__ __launch_bounds__(256) void chamfer_reduce_kernel(
        const float* __restrict__ part,
        const float* __restrict__ xm, const float* __restrict__ ym,
        double* __restrict__ acc, unsigned* __restrict__ cnt,
        float* __restrict__ out) {
    const int id  = blockIdx.x * 256 + threadIdx.x;
    const int dir = id >> 15;            // uniform per wave
    const int rem = id & 32767;
    const int b   = rem >> 12;
    const int n   = rem & (N_ - 1);

    const float* msk = dir ? ym : xm;

    float mn = 1e30f;
#pragma unroll
    for (int oc = 0; oc < OPP_CHUNKS; ++oc)
        mn = fminf(mn, part[(((size_t)dir * B_ + b) * OPP_CHUNKS + oc) * N_ + n]);

    double val = (double)(msk[(size_t)b * N_ + n] * mn);
    for (int off = 32; off; off >>= 1)
        val += __shfl_down(val, off);
    if ((threadIdx.x & 63) == 0)
        atomicAdd(&acc[dir], val);

    __syncthreads();
    if (threadIdx.x == 0) {
        __threadfence();
        unsigned old = atomicAdd(cnt, 1u);
        if (old == RED_BLOCKS - 1) {
            __threadfence();
            double d = (acc[0] - acc[1]) / (double)(B_ * N_);
            out[0] = (float)(d * d);
        }
    }
}

extern "C" void kernel_launch(void* const* d_in, const int* in_sizes, int n_in,
                              void* d_out, int out_size, void* d_ws, size_t ws_size,
                              hipStream_t stream) {
    const float* x  = (const float*)d_in[0];
    const float* y  = (const float*)d_in[1];
    const float* xm = (const float*)d_in[2];
    const float* ym = (const float*)d_in[3];
    float* out = (float*)d_out;

    double*   acc = (double*)d_ws;                          // 16 B
    unsigned* cnt = (unsigned*)((char*)d_ws + 16);          // 4 B
    float4*   tab = (float4*)((char*)d_ws + 256);           // 2*8*4096*16 = 1 MB
    float*    prt = (float*)((char*)d_ws + 256 + (size_t)2 * B_ * N_ * 16); // 4 MB

    chamfer_prep<<<RED_BLOCKS, 256, 0, stream>>>(x, y, tab, acc, cnt);

    dim3 grid(OWN_CHUNKS, B_ * OPP_CHUNKS, 2);              // 2048 blocks
    chamfer_min_kernel<<<grid, 256, 0, stream>>>(x, y, tab, prt);

    chamfer_reduce_kernel<<<RED_BLOCKS, 256, 0, stream>>>(prt, xm, ym, acc, cnt, out);
}